// Round 1
// baseline (247.190 us; speedup 1.0000x reference)
//
#include <hip/hip_runtime.h>

#define OUT_DIM 4096
#define DPC     16
#define NCOL    65536   // OUT_DIM * DPC
#define BATCH   512
#define TOTAL_W (BATCH * OUT_DIM)   // 2,097,152 windows

// Kernel 1: precompute boost factors bf[p] = exp((1/16 - duty[p]) * bs)
// Double-precision exp rounded to fp32 => correctly-rounded result, minimizes
// argmax-flip risk vs the numpy reference's float32 exp.
__global__ void boost_table_kernel(const float* __restrict__ duty,
                                   const float* __restrict__ bs_ptr,
                                   float* __restrict__ bf) {
    int p = blockIdx.x * blockDim.x + threadIdx.x;
    if (p < NCOL) {
        float t = (0.0625f - duty[p]) * bs_ptr[0];
        bf[p] = (float)exp((double)t);
    }
}

// Kernel 2: one 16-lane group per window, 4 windows per wave64.
// Lane j of the group:
//   - reads x[b, 15w+j] * bf[15w+j]  (argmax input, windows stride 15)
//   - butterfly-max over the 16-lane group with first-index tie-break
//   - writes out[b, 16w+j] = (j == jstar) ? x[b, 16w+j] : 0   (stride 16)
__global__ __launch_bounds__(256) void dkw_kernel(const float* __restrict__ x,
                                                  const float* __restrict__ bf,
                                                  float* __restrict__ out) {
    const int lane = threadIdx.x & 63;
    const int wave = threadIdx.x >> 6;     // 0..3
    const int j    = lane & 15;            // position within window
    const int sub  = lane >> 4;            // 0..3, window within wave
    const unsigned inv_j = 15u - (unsigned)j;

    int W = (blockIdx.x * 4 + wave) * 4 + sub;      // global window id
    const int strideW = gridDim.x * 16;             // windows per grid pass

    for (; W < TOTAL_W; W += strideW) {
        const int b = W >> 12;                      // 4096 windows per row
        const int w = W & 4095;
        const int rowbase = b << 16;                // b * 65536 (fits in int)

        const int col_in = w * 15 + j;              // window read column
        float v   = x[rowbase + col_in];
        float bfv = bf[col_in];
        float boosted = v * bfv;

        // order-preserving uint mapping of float
        unsigned ub  = __float_as_uint(boosted);
        unsigned ord = ((int)ub < 0) ? ~ub : (ub | 0x80000000u);
        // key: [ord : 32][15-j : 4] -> larger key == (larger value, smaller j)
        unsigned long long key = ((unsigned long long)ord << 4) | inv_j;

        #pragma unroll
        for (int m = 1; m <= 8; m <<= 1) {
            unsigned long long other =
                (unsigned long long)__shfl_xor((long long)key, m);
            if (other > key) key = other;
        }
        const int jstar = 15 - (int)(key & 15ull);

        const int oidx = rowbase + (w << 4) + j;    // output column (stride 16!)
        float xo = x[oidx];
        out[oidx] = (j == jstar) ? xo : 0.0f;
    }
}

extern "C" void kernel_launch(void* const* d_in, const int* in_sizes, int n_in,
                              void* d_out, int out_size, void* d_ws, size_t ws_size,
                              hipStream_t stream) {
    const float* x    = (const float*)d_in[0];
    const float* duty = (const float*)d_in[1];
    const float* bs   = (const float*)d_in[2];
    float* out = (float*)d_out;
    float* bf  = (float*)d_ws;   // 65536 floats = 256 KiB scratch

    hipLaunchKernelGGL(boost_table_kernel, dim3(NCOL / 256), dim3(256), 0, stream,
                       duty, bs, bf);
    hipLaunchKernelGGL(dkw_kernel, dim3(4096), dim3(256), 0, stream,
                       x, bf, out);
}